// Round 1
// baseline (791.347 us; speedup 1.0000x reference)
//
#include <hip/hip_runtime.h>

// Problem constants (from reference)
#define B_  2
#define N_  20000
#define C_  256
#define K_  5000
#define M_  (B_ * K_)    // 10000
#define MP_ 10240        // M padded to multiple of 64 for GEMM

// ---------------------------------------------------------------------------
// float -> orderable uint (descending score, then ascending index handled
// separately). Scores are >= 0 but be robust anyway.
__device__ __forceinline__ unsigned fkey(float f) {
  unsigned u = __float_as_uint(f);
  return (u & 0x80000000u) ? ~u : (u | 0x80000000u);
}

// ---------------------------------------------------------------------------
// Exact rank of every element among its batch (descending score, stable ties
// by lower index == jax.lax.top_k). rank < K  =>  keep at position rank.
__global__ __launch_bounds__(256) void k_rank(const float* __restrict__ score,
                                              int* __restrict__ keep_i,
                                              float* __restrict__ keep_f) {
  const int b = blockIdx.y;
  const int tid = threadIdx.x;
  const int j = blockIdx.x * 256 + tid;
  const float* s = score + b * N_;
  unsigned myk = 0;
  if (j < N_) myk = fkey(s[j]);
  __shared__ unsigned sk[256];
  int cnt = 0;
  const int ntiles = (N_ + 255) / 256;
  for (int t = 0; t < ntiles; ++t) {
    const int gi = t * 256 + tid;
    unsigned kk = 0;  // sentinel: never counts (valid keys have MSB set)
    if (gi < N_) kk = fkey(s[gi]);
    __syncthreads();
    sk[tid] = kk;
    __syncthreads();
    const uint4* sk4 = (const uint4*)sk;
    const int base = t * 256;
#pragma unroll 8
    for (int q = 0; q < 64; ++q) {
      uint4 v = sk4[q];
      const int gb = base + q * 4;
      cnt += (int)(v.x > myk) + (int)((v.x == myk) & (gb     < j));
      cnt += (int)(v.y > myk) + (int)((v.y == myk) & (gb + 1 < j));
      cnt += (int)(v.z > myk) + (int)((v.z == myk) & (gb + 2 < j));
      cnt += (int)(v.w > myk) + (int)((v.w == myk) & (gb + 3 < j));
    }
  }
  if (j < N_ && cnt < K_) {
    keep_i[b * K_ + cnt] = j;
    keep_f[b * K_ + cnt] = (float)j;  // keep output, as float values
  }
}

// ---------------------------------------------------------------------------
// Gather kept boxes into [B*K][4] (xyxy) and zero the max-iou accumulator.
__global__ __launch_bounds__(256) void k_gatherbox(const int* __restrict__ keep_i,
                                                   const float* __restrict__ box,
                                                   float* __restrict__ boxK,
                                                   unsigned* __restrict__ maxiou) {
  const int t = blockIdx.x * 256 + threadIdx.x;
  if (t >= B_ * K_) return;
  const int b = t / K_;
  const int idx = keep_i[t];
  const float* bb = box + (size_t)b * 4 * N_;
  float4 v;
  v.x = bb[0 * N_ + idx];
  v.y = bb[1 * N_ + idx];
  v.z = bb[2 * N_ + idx];
  v.w = bb[3 * N_ + idx];
  ((float4*)boxK)[t] = v;
  maxiou[t] = 0u;
}

// ---------------------------------------------------------------------------
// For each kept box j: max over i<j of IoU(i,j), accumulated via atomicMax on
// float bits (IoU >= 0). Triangular tiling: block (jt, it, b), it <= jt.
// IoU arithmetic uses _rn intrinsics to match numpy f32 bit-exactly
// (threshold comparisons are discrete decisions).
__global__ __launch_bounds__(256) void k_iou(const float* __restrict__ boxK,
                                             unsigned* __restrict__ maxiou) {
  const int jt = blockIdx.x;
  const int it = blockIdx.y;
  if (it > jt) return;
  const int b = blockIdx.z;
  const int tid = threadIdx.x;
  __shared__ float sx0[256], sy0[256], sx1[256], sy1[256], sa[256];
  const int gi0 = it * 256;
  const int gl = gi0 + tid;
  if (gl < K_) {
    float4 v = ((const float4*)boxK)[b * K_ + gl];
    sx0[tid] = v.x; sy0[tid] = v.y; sx1[tid] = v.z; sy1[tid] = v.w;
    sa[tid] = __fmul_rn(__fsub_rn(v.z, v.x), __fsub_rn(v.w, v.y));
  } else {
    sx0[tid] = 1e30f; sy0[tid] = 1e30f; sx1[tid] = -1e30f; sy1[tid] = -1e30f;
    sa[tid] = 0.f;
  }
  __syncthreads();
  const int j = jt * 256 + tid;
  if (j >= K_) return;
  float4 v = ((const float4*)boxK)[b * K_ + j];
  const float aj = __fmul_rn(__fsub_rn(v.z, v.x), __fsub_rn(v.w, v.y));
  float mx = 0.f;
  int lim = j - gi0;
  if (lim > 256) lim = 256;
  for (int ii = 0; ii < lim; ++ii) {
    float ltx = fmaxf(sx0[ii], v.x);
    float lty = fmaxf(sy0[ii], v.y);
    float rbx = fminf(sx1[ii], v.z);
    float rby = fminf(sy1[ii], v.w);
    float wx = fmaxf(__fsub_rn(rbx, ltx), 0.f);
    float wy = fmaxf(__fsub_rn(rby, lty), 0.f);
    float inter = __fmul_rn(wx, wy);
    if (inter > 0.f) {
      float uni = __fsub_rn(__fadd_rn(sa[ii], aj), inter);
      float iou = __fdiv_rn(inter, uni);
      mx = fmaxf(mx, iou);
    }
  }
  if (mx > 0.f) atomicMax(&maxiou[b * K_ + j], __float_as_uint(mx));
}

// ---------------------------------------------------------------------------
// Gather kept features into X [C][MP_] (pad columns m>=M_ set to 0).
__global__ __launch_bounds__(256) void k_gatherfeat(const int* __restrict__ keep_i,
                                                    const float* __restrict__ feat,
                                                    float* __restrict__ X) {
  const int t = blockIdx.x * 256 + threadIdx.x;  // t = c*MP_ + m
  const int m = t % MP_;
  const int c = t / MP_;
  float v = 0.f;
  if (m < M_) {
    const int b = m / K_;
    const int idx = keep_i[m];
    v = feat[((size_t)(b * C_ + c)) * N_ + idx];
  }
  X[t] = v;
}

// ---------------------------------------------------------------------------
// Y[o][m] = leaky_relu( sum_c W[o][c] * X[c][m] + bias[o], 0.2 )
// 64x64 block tile, BK=16, 256 threads, 4x4 micro-tile.
__global__ __launch_bounds__(256) void k_gemm_lrelu(const float* __restrict__ W,
                                                    const float* __restrict__ bias,
                                                    const float* __restrict__ X,
                                                    float* __restrict__ Y) {
  __shared__ float As[16][68];  // W tile transposed, padded (16B-aligned rows)
  __shared__ float Bs[16][64];
  const int bn = blockIdx.x * 64;  // m base
  const int bm = blockIdx.y * 64;  // o base
  const int tid = threadIdx.x;
  const int tx = tid & 15;
  const int ty = tid >> 4;
  const int jj = tid & 63;
  const int kk = tid >> 6;
  float acc[4][4] = {};
  for (int c0 = 0; c0 < C_; c0 += 16) {
#pragma unroll
    for (int r = 0; r < 4; ++r)
      As[tx][ty + r * 16] = W[(bm + ty + r * 16) * C_ + c0 + tx];
#pragma unroll
    for (int r = 0; r < 4; ++r)
      Bs[kk + r * 4][jj] = X[(c0 + kk + r * 4) * MP_ + bn + jj];
    __syncthreads();
#pragma unroll
    for (int k = 0; k < 16; ++k) {
      float4 a = *(const float4*)&As[k][ty * 4];
      float4 bv = *(const float4*)&Bs[k][tx * 4];
      const float av[4] = {a.x, a.y, a.z, a.w};
      const float bw[4] = {bv.x, bv.y, bv.z, bv.w};
#pragma unroll
      for (int i = 0; i < 4; ++i)
#pragma unroll
        for (int q = 0; q < 4; ++q)
          acc[i][q] += av[i] * bw[q];
    }
    __syncthreads();
  }
#pragma unroll
  for (int i = 0; i < 4; ++i) {
    const int o = bm + ty * 4 + i;
    const float bv = bias[o];
    float4 out;
    float t0 = acc[i][0] + bv; out.x = fmaxf(t0, 0.2f * t0);
    float t1 = acc[i][1] + bv; out.y = fmaxf(t1, 0.2f * t1);
    float t2 = acc[i][2] + bv; out.z = fmaxf(t2, 0.2f * t2);
    float t3 = acc[i][3] + bv; out.w = fmaxf(t3, 0.2f * t3);
    *(float4*)&Y[(size_t)o * MP_ + bn + tx * 4] = out;
  }
}

// ---------------------------------------------------------------------------
// Final: logits = Wf @ x + bf (3 rows), softmax over 3, loc = sum_t mask_t*p_t
// with mask_t = (max_{i<j} iou < thr_t).
__global__ __launch_bounds__(256) void k_final(const float* __restrict__ X,
                                               const float* __restrict__ Wf,
                                               const float* __restrict__ bf,
                                               const unsigned* __restrict__ maxiou,
                                               float* __restrict__ out_loc) {
  __shared__ float sw[3 * 256];
  const int tid = threadIdx.x;
  sw[tid] = Wf[tid];
  sw[256 + tid] = Wf[256 + tid];
  sw[512 + tid] = Wf[512 + tid];
  __syncthreads();
  const int m = blockIdx.x * 256 + tid;
  if (m >= M_) return;
  float a0 = 0.f, a1 = 0.f, a2 = 0.f;
#pragma unroll 4
  for (int c = 0; c < C_; ++c) {
    const float x = X[c * MP_ + m];
    a0 += sw[c] * x;
    a1 += sw[256 + c] * x;
    a2 += sw[512 + c] * x;
  }
  a0 += bf[0]; a1 += bf[1]; a2 += bf[2];
  const float mxv = fmaxf(a0, fmaxf(a1, a2));
  const float e0 = expf(a0 - mxv);
  const float e1 = expf(a1 - mxv);
  const float e2 = expf(a2 - mxv);
  const float inv = 1.f / (e0 + e1 + e2);
  const float miou = __uint_as_float(maxiou[m]);
  float loc = 0.f;
  if (miou < 0.4f) loc += e0;
  if (miou < 0.6f) loc += e1;
  if (miou < 0.8f) loc += e2;
  out_loc[m] = loc * inv;
}

// ---------------------------------------------------------------------------
extern "C" void kernel_launch(void* const* d_in, const int* in_sizes, int n_in,
                              void* d_out, int out_size, void* d_ws, size_t ws_size,
                              hipStream_t stream) {
  const float* box   = (const float*)d_in[0];  // [B,4,N]
  const float* score = (const float*)d_in[1];  // [B,1,N]
  const float* feat  = (const float*)d_in[2];  // [B,C,N]
  const float* W     = (const float*)d_in[3];  // [6,C,C]
  const float* bias  = (const float*)d_in[4];  // [6,C]
  const float* Wf    = (const float*)d_in[5];  // [3,C]
  const float* bf    = (const float*)d_in[6];  // [3]

  float* out = (float*)d_out;
  float* out_loc  = out;            // [B*K] loc_max
  float* out_keep = out + M_;       // [B*K] keep (as float values)

  // Workspace layout (256B-aligned offsets), total ~20.3 MB
  char* ws = (char*)d_ws;
  int*      keep_i = (int*)(ws + 0);             //  40000 B
  float*    boxK   = (float*)(ws + 40960);       // 160000 B
  unsigned* maxiou = (unsigned*)(ws + 204800);   //  40000 B
  float*    X0     = (float*)(ws + 262144);      // 10485760 B
  float*    X1     = (float*)(ws + 10747904);    // 10485760 B

  k_rank<<<dim3((N_ + 255) / 256, B_), 256, 0, stream>>>(score, keep_i, out_keep);
  k_gatherbox<<<(B_ * K_ + 255) / 256, 256, 0, stream>>>(keep_i, box, boxK, maxiou);
  k_iou<<<dim3((K_ + 255) / 256, (K_ + 255) / 256, B_), 256, 0, stream>>>(boxK, maxiou);
  k_gatherfeat<<<(C_ * MP_) / 256, 256, 0, stream>>>(keep_i, feat, X0);

  const float* xin = X0;
  float* xout = X1;
  for (int l = 0; l < 6; ++l) {
    k_gemm_lrelu<<<dim3(MP_ / 64, C_ / 64), 256, 0, stream>>>(
        W + (size_t)l * C_ * C_, bias + (size_t)l * C_, xin, xout);
    const float* tmp = xout;
    xout = (float*)xin;
    xin = tmp;
  }
  // after 6 layers, activations are in X0 (xin points at it)

  k_final<<<(M_ + 255) / 256, 256, 0, stream>>>(xin, Wf, bf, maxiou, out_loc);
}

// Round 2
// 393.517 us; speedup vs baseline: 2.0110x; 2.0110x over previous
//
#include <hip/hip_runtime.h>

// Problem constants (from reference)
#define B_  2
#define N_  20000
#define C_  256
#define K_  5000
#define M_  (B_ * K_)    // 10000
#define MP_ 10240        // M padded to multiple of 64 for GEMM

#define NT_    79   // ceil(N_/256) key tiles
#define CHUNK_ 8    // key tiles per k_count block
#define NCH_   10   // ceil(NT_/CHUNK_)

// ---------------------------------------------------------------------------
// float -> orderable uint (descending). Scores >= 0 but robust anyway.
__device__ __forceinline__ unsigned fkey(float f) {
  unsigned u = __float_as_uint(f);
  return (u & 0x80000000u) ? ~u : (u | 0x80000000u);
}

// Composite 64-bit key: higher = earlier in top-k order.
// Ties (equal score) broken by LOWER index first -> idx part = N_-1-j.
__device__ __forceinline__ unsigned long long ckey(float f, int j) {
  return ((unsigned long long)fkey(f) << 32) | (unsigned)(N_ - 1 - j);
}

// ---------------------------------------------------------------------------
__global__ __launch_bounds__(256) void k_zero(int* __restrict__ cnt) {
  const int t = blockIdx.x * 256 + threadIdx.x;
  if (t < B_ * N_) cnt[t] = 0;
}

// ---------------------------------------------------------------------------
// Partial exact-rank: block (jt, ch, b) compares j-tile jt against key tiles
// [ch*CHUNK_, (ch+1)*CHUNK_), atomicAdd partial count into cnt[b][j].
__global__ __launch_bounds__(256) void k_count(const float* __restrict__ score,
                                               int* __restrict__ cnt) {
  const int jt = blockIdx.x;
  const int ch = blockIdx.y;
  const int b = blockIdx.z;
  const int tid = threadIdx.x;
  const int j = jt * 256 + tid;
  const float* s = score + b * N_;
  unsigned long long myk = 0;
  if (j < N_) myk = ckey(s[j], j);
  __shared__ unsigned long long sk[256];
  int c = 0;
  const int t0 = ch * CHUNK_;
  int t1 = t0 + CHUNK_;
  if (t1 > NT_) t1 = NT_;
  for (int t = t0; t < t1; ++t) {
    const int gi = t * 256 + tid;
    unsigned long long kk = 0;  // sentinel < every valid key
    if (gi < N_) kk = ckey(s[gi], gi);
    __syncthreads();
    sk[tid] = kk;
    __syncthreads();
#pragma unroll 16
    for (int ii = 0; ii < 256; ++ii) c += (int)(sk[ii] > myk);
  }
  if (j < N_ && c > 0) atomicAdd(&cnt[b * N_ + j], c);
}

// ---------------------------------------------------------------------------
__global__ __launch_bounds__(256) void k_scatter(const int* __restrict__ cnt,
                                                 int* __restrict__ keep_i,
                                                 float* __restrict__ keep_f) {
  const int b = blockIdx.y;
  const int j = blockIdx.x * 256 + threadIdx.x;
  if (j >= N_) return;
  const int r = cnt[b * N_ + j];
  if (r < K_) {
    keep_i[b * K_ + r] = j;
    keep_f[b * K_ + r] = (float)j;
  }
}

// ---------------------------------------------------------------------------
// Gather kept boxes into [B*K][4] (xyxy) and zero the max-iou accumulator.
__global__ __launch_bounds__(256) void k_gatherbox(const int* __restrict__ keep_i,
                                                   const float* __restrict__ box,
                                                   float* __restrict__ boxK,
                                                   unsigned* __restrict__ maxiou) {
  const int t = blockIdx.x * 256 + threadIdx.x;
  if (t >= B_ * K_) return;
  const int b = t / K_;
  const int idx = keep_i[t];
  const float* bb = box + (size_t)b * 4 * N_;
  float4 v;
  v.x = bb[0 * N_ + idx];
  v.y = bb[1 * N_ + idx];
  v.z = bb[2 * N_ + idx];
  v.w = bb[3 * N_ + idx];
  ((float4*)boxK)[t] = v;
  maxiou[t] = 0u;
}

// ---------------------------------------------------------------------------
// For each kept box j: max over i<j of IoU(i,j), accumulated via atomicMax on
// float bits (IoU >= 0). Triangular tiling: block (jt, it, b), it <= jt.
// _rn intrinsics keep IoU bit-identical to the numpy f32 reference (threshold
// comparisons are discrete decisions).
__global__ __launch_bounds__(256) void k_iou(const float* __restrict__ boxK,
                                             unsigned* __restrict__ maxiou) {
  const int jt = blockIdx.x;
  const int it = blockIdx.y;
  if (it > jt) return;
  const int b = blockIdx.z;
  const int tid = threadIdx.x;
  __shared__ float sx0[256], sy0[256], sx1[256], sy1[256], sa[256];
  const int gi0 = it * 256;
  const int gl = gi0 + tid;
  if (gl < K_) {
    float4 v = ((const float4*)boxK)[b * K_ + gl];
    sx0[tid] = v.x; sy0[tid] = v.y; sx1[tid] = v.z; sy1[tid] = v.w;
    sa[tid] = __fmul_rn(__fsub_rn(v.z, v.x), __fsub_rn(v.w, v.y));
  } else {
    sx0[tid] = 1e30f; sy0[tid] = 1e30f; sx1[tid] = -1e30f; sy1[tid] = -1e30f;
    sa[tid] = 0.f;
  }
  __syncthreads();
  const int j = jt * 256 + tid;
  if (j >= K_) return;
  float4 v = ((const float4*)boxK)[b * K_ + j];
  const float aj = __fmul_rn(__fsub_rn(v.z, v.x), __fsub_rn(v.w, v.y));
  float mx = 0.f;
  int lim = j - gi0;
  if (lim > 256) lim = 256;
  for (int ii = 0; ii < lim; ++ii) {
    float ltx = fmaxf(sx0[ii], v.x);
    float lty = fmaxf(sy0[ii], v.y);
    float rbx = fminf(sx1[ii], v.z);
    float rby = fminf(sy1[ii], v.w);
    float wx = fmaxf(__fsub_rn(rbx, ltx), 0.f);
    float wy = fmaxf(__fsub_rn(rby, lty), 0.f);
    float inter = __fmul_rn(wx, wy);
    if (inter > 0.f) {
      float uni = __fsub_rn(__fadd_rn(sa[ii], aj), inter);
      float iou = __fdiv_rn(inter, uni);
      mx = fmaxf(mx, iou);
    }
  }
  if (mx > 0.f) atomicMax(&maxiou[b * K_ + j], __float_as_uint(mx));
}

// ---------------------------------------------------------------------------
// Gather kept features into X [C][MP_] (pad columns m>=M_ set to 0).
__global__ __launch_bounds__(256) void k_gatherfeat(const int* __restrict__ keep_i,
                                                    const float* __restrict__ feat,
                                                    float* __restrict__ X) {
  const int t = blockIdx.x * 256 + threadIdx.x;  // t = c*MP_ + m
  const int m = t % MP_;
  const int c = t / MP_;
  float v = 0.f;
  if (m < M_) {
    const int b = m / K_;
    const int idx = keep_i[m];
    v = feat[((size_t)(b * C_ + c)) * N_ + idx];
  }
  X[t] = v;
}

// ---------------------------------------------------------------------------
// Y[o][m] = leaky_relu( sum_c W[o][c] * X[c][m] + bias[o], 0.2 )
// 64x64 block tile, BK=16, 256 threads, 4x4 micro-tile.
__global__ __launch_bounds__(256) void k_gemm_lrelu(const float* __restrict__ W,
                                                    const float* __restrict__ bias,
                                                    const float* __restrict__ X,
                                                    float* __restrict__ Y) {
  __shared__ float As[16][68];  // W tile transposed, padded
  __shared__ float Bs[16][64];
  const int bn = blockIdx.x * 64;  // m base
  const int bm = blockIdx.y * 64;  // o base
  const int tid = threadIdx.x;
  const int tx = tid & 15;
  const int ty = tid >> 4;
  const int jj = tid & 63;
  const int kk = tid >> 6;
  float acc[4][4] = {};
  for (int c0 = 0; c0 < C_; c0 += 16) {
#pragma unroll
    for (int r = 0; r < 4; ++r)
      As[tx][ty + r * 16] = W[(bm + ty + r * 16) * C_ + c0 + tx];
#pragma unroll
    for (int r = 0; r < 4; ++r)
      Bs[kk + r * 4][jj] = X[(c0 + kk + r * 4) * MP_ + bn + jj];
    __syncthreads();
#pragma unroll
    for (int k = 0; k < 16; ++k) {
      float4 a = *(const float4*)&As[k][ty * 4];
      float4 bv = *(const float4*)&Bs[k][tx * 4];
      const float av[4] = {a.x, a.y, a.z, a.w};
      const float bw[4] = {bv.x, bv.y, bv.z, bv.w};
#pragma unroll
      for (int i = 0; i < 4; ++i)
#pragma unroll
        for (int q = 0; q < 4; ++q)
          acc[i][q] += av[i] * bw[q];
    }
    __syncthreads();
  }
#pragma unroll
  for (int i = 0; i < 4; ++i) {
    const int o = bm + ty * 4 + i;
    const float bv = bias[o];
    float4 out;
    float t0 = acc[i][0] + bv; out.x = fmaxf(t0, 0.2f * t0);
    float t1 = acc[i][1] + bv; out.y = fmaxf(t1, 0.2f * t1);
    float t2 = acc[i][2] + bv; out.z = fmaxf(t2, 0.2f * t2);
    float t3 = acc[i][3] + bv; out.w = fmaxf(t3, 0.2f * t3);
    *(float4*)&Y[(size_t)o * MP_ + bn + tx * 4] = out;
  }
}

// ---------------------------------------------------------------------------
// Final: logits = Wf @ x + bf (3 rows), softmax over 3, loc = sum_t mask_t*p_t
// with mask_t = (max_{i<j} iou < thr_t).
__global__ __launch_bounds__(256) void k_final(const float* __restrict__ X,
                                               const float* __restrict__ Wf,
                                               const float* __restrict__ bf,
                                               const unsigned* __restrict__ maxiou,
                                               float* __restrict__ out_loc) {
  __shared__ float sw[3 * 256];
  const int tid = threadIdx.x;
  sw[tid] = Wf[tid];
  sw[256 + tid] = Wf[256 + tid];
  sw[512 + tid] = Wf[512 + tid];
  __syncthreads();
  const int m = blockIdx.x * 256 + tid;
  if (m >= M_) return;
  float a0 = 0.f, a1 = 0.f, a2 = 0.f;
#pragma unroll 4
  for (int c = 0; c < C_; ++c) {
    const float x = X[c * MP_ + m];
    a0 += sw[c] * x;
    a1 += sw[256 + c] * x;
    a2 += sw[512 + c] * x;
  }
  a0 += bf[0]; a1 += bf[1]; a2 += bf[2];
  const float mxv = fmaxf(a0, fmaxf(a1, a2));
  const float e0 = expf(a0 - mxv);
  const float e1 = expf(a1 - mxv);
  const float e2 = expf(a2 - mxv);
  const float inv = 1.f / (e0 + e1 + e2);
  const float miou = __uint_as_float(maxiou[m]);
  float loc = 0.f;
  if (miou < 0.4f) loc += e0;
  if (miou < 0.6f) loc += e1;
  if (miou < 0.8f) loc += e2;
  out_loc[m] = loc * inv;
}

// ---------------------------------------------------------------------------
extern "C" void kernel_launch(void* const* d_in, const int* in_sizes, int n_in,
                              void* d_out, int out_size, void* d_ws, size_t ws_size,
                              hipStream_t stream) {
  const float* box   = (const float*)d_in[0];  // [B,4,N]
  const float* score = (const float*)d_in[1];  // [B,1,N]
  const float* feat  = (const float*)d_in[2];  // [B,C,N]
  const float* W     = (const float*)d_in[3];  // [6,C,C]
  const float* bias  = (const float*)d_in[4];  // [6,C]
  const float* Wf    = (const float*)d_in[5];  // [3,C]
  const float* bf    = (const float*)d_in[6];  // [3]

  float* out = (float*)d_out;
  float* out_loc  = out;            // [B*K] loc_max
  float* out_keep = out + M_;       // [B*K] keep (as float values)

  // Workspace layout (unchanged footprint ~21.2 MB)
  char* ws = (char*)d_ws;
  int*      keep_i = (int*)(ws + 0);             //  40000 B
  float*    boxK   = (float*)(ws + 40960);       // 160000 B
  unsigned* maxiou = (unsigned*)(ws + 204800);   //  40000 B
  float*    X0     = (float*)(ws + 262144);      // 10485760 B
  float*    X1     = (float*)(ws + 10747904);    // 10485760 B
  // cnt[B][N] (160 KB) aliases X1: cnt's lifetime (k_zero..k_scatter) ends
  // before GEMM layer 0 writes X1.
  int*      cnt    = (int*)(ws + 10747904);

  k_zero<<<(B_ * N_ + 255) / 256, 256, 0, stream>>>(cnt);
  k_count<<<dim3(NT_, NCH_, B_), 256, 0, stream>>>(score, cnt);
  k_scatter<<<dim3(NT_, B_), 256, 0, stream>>>(cnt, keep_i, out_keep);
  k_gatherbox<<<(B_ * K_ + 255) / 256, 256, 0, stream>>>(keep_i, box, boxK, maxiou);
  k_iou<<<dim3((K_ + 255) / 256, (K_ + 255) / 256, B_), 256, 0, stream>>>(boxK, maxiou);
  k_gatherfeat<<<(C_ * MP_) / 256, 256, 0, stream>>>(keep_i, feat, X0);

  const float* xin = X0;
  float* xout = X1;
  for (int l = 0; l < 6; ++l) {
    k_gemm_lrelu<<<dim3(MP_ / 64, C_ / 64), 256, 0, stream>>>(
        W + (size_t)l * C_ * C_, bias + (size_t)l * C_, xin, xout);
    const float* tmp = xout;
    xout = (float*)xin;
    xin = tmp;
  }
  // after 6 layers, activations are in X0 (xin points at it)

  k_final<<<(M_ + 255) / 256, 256, 0, stream>>>(xin, Wf, bf, maxiou, out_loc);
}

// Round 3
// 326.699 us; speedup vs baseline: 2.4222x; 1.2045x over previous
//
#include <hip/hip_runtime.h>

// Problem constants (from reference)
#define B_  2
#define N_  20000
#define C_  256
#define K_  5000
#define M_  (B_ * K_)    // 10000
#define MP_ 10240        // M padded (multiple of 128 for GEMM tiles)

#define NT_    79   // ceil(N_/256) key tiles
#define CHUNK_ 8    // key tiles per k_count block
#define NCH_   10   // ceil(NT_/CHUNK_)

typedef __attribute__((ext_vector_type(8))) short bf16x8;
typedef __attribute__((ext_vector_type(4))) float f32x4;
typedef __attribute__((ext_vector_type(2))) unsigned long long ull2;

// ---------------------------------------------------------------------------
// bf16 helpers (RNE)
__device__ __forceinline__ unsigned short f2bf(float x) {
  unsigned u = __float_as_uint(x);
  unsigned r = (u + 0x7fffu + ((u >> 16) & 1u)) >> 16;
  return (unsigned short)r;
}
__device__ __forceinline__ float bf2f(unsigned short h) {
  return __uint_as_float(((unsigned)h) << 16);
}

// ---------------------------------------------------------------------------
// float -> orderable uint (descending). Scores >= 0 but robust anyway.
__device__ __forceinline__ unsigned fkey(float f) {
  unsigned u = __float_as_uint(f);
  return (u & 0x80000000u) ? ~u : (u | 0x80000000u);
}
// Composite 64-bit key: higher = earlier in top-k order; ties by LOWER index.
__device__ __forceinline__ unsigned long long ckey(float f, int j) {
  return ((unsigned long long)fkey(f) << 32) | (unsigned)(N_ - 1 - j);
}

// ---------------------------------------------------------------------------
__global__ __launch_bounds__(256) void k_zero(int* __restrict__ cnt) {
  const int t = blockIdx.x * 256 + threadIdx.x;
  if (t < B_ * N_) cnt[t] = 0;
}

// ---------------------------------------------------------------------------
// Partial exact-rank: block (jt, ch, b) compares j-tile jt against key tiles
// [ch*CHUNK_, (ch+1)*CHUNK_), atomicAdd partial count into cnt[b][j].
__global__ __launch_bounds__(256) void k_count(const float* __restrict__ score,
                                               int* __restrict__ cnt) {
  const int jt = blockIdx.x;
  const int ch = blockIdx.y;
  const int b = blockIdx.z;
  const int tid = threadIdx.x;
  const int j = jt * 256 + tid;
  const float* s = score + b * N_;
  unsigned long long myk = 0;
  if (j < N_) myk = ckey(s[j], j);
  __shared__ unsigned long long sk[256];
  int c = 0;
  const int t0 = ch * CHUNK_;
  int t1 = t0 + CHUNK_;
  if (t1 > NT_) t1 = NT_;
  for (int t = t0; t < t1; ++t) {
    const int gi = t * 256 + tid;
    unsigned long long kk = 0;  // sentinel < every valid key
    if (gi < N_) kk = ckey(s[gi], gi);
    __syncthreads();
    sk[tid] = kk;
    __syncthreads();
#pragma unroll 8
    for (int ii = 0; ii < 256; ii += 2) {
      ull2 v = *(const ull2*)&sk[ii];
      c += (int)(v.x > myk);
      c += (int)(v.y > myk);
    }
  }
  if (j < N_ && c > 0) atomicAdd(&cnt[b * N_ + j], c);
}

// ---------------------------------------------------------------------------
__global__ __launch_bounds__(256) void k_scatter(const int* __restrict__ cnt,
                                                 int* __restrict__ keep_i,
                                                 float* __restrict__ keep_f) {
  const int b = blockIdx.y;
  const int j = blockIdx.x * 256 + threadIdx.x;
  if (j >= N_) return;
  const int r = cnt[b * N_ + j];
  if (r < K_) {
    keep_i[b * K_ + r] = j;
    keep_f[b * K_ + r] = (float)j;
  }
}

// ---------------------------------------------------------------------------
__global__ __launch_bounds__(256) void k_gatherbox(const int* __restrict__ keep_i,
                                                   const float* __restrict__ box,
                                                   float* __restrict__ boxK,
                                                   unsigned* __restrict__ maxiou) {
  const int t = blockIdx.x * 256 + threadIdx.x;
  if (t >= B_ * K_) return;
  const int b = t / K_;
  const int idx = keep_i[t];
  const float* bb = box + (size_t)b * 4 * N_;
  float4 v;
  v.x = bb[0 * N_ + idx];
  v.y = bb[1 * N_ + idx];
  v.z = bb[2 * N_ + idx];
  v.w = bb[3 * N_ + idx];
  ((float4*)boxK)[t] = v;
  maxiou[t] = 0u;
}

// ---------------------------------------------------------------------------
// max over i<j of IoU(i,j) via atomicMax on float bits. _rn intrinsics keep
// IoU bit-identical to the numpy f32 reference (discrete threshold decisions).
__global__ __launch_bounds__(256) void k_iou(const float* __restrict__ boxK,
                                             unsigned* __restrict__ maxiou) {
  const int jt = blockIdx.x;
  const int it = blockIdx.y;
  if (it > jt) return;
  const int b = blockIdx.z;
  const int tid = threadIdx.x;
  __shared__ float sx0[256], sy0[256], sx1[256], sy1[256], sa[256];
  const int gi0 = it * 256;
  const int gl = gi0 + tid;
  if (gl < K_) {
    float4 v = ((const float4*)boxK)[b * K_ + gl];
    sx0[tid] = v.x; sy0[tid] = v.y; sx1[tid] = v.z; sy1[tid] = v.w;
    sa[tid] = __fmul_rn(__fsub_rn(v.z, v.x), __fsub_rn(v.w, v.y));
  } else {
    sx0[tid] = 1e30f; sy0[tid] = 1e30f; sx1[tid] = -1e30f; sy1[tid] = -1e30f;
    sa[tid] = 0.f;
  }
  __syncthreads();
  const int j = jt * 256 + tid;
  if (j >= K_) return;
  float4 v = ((const float4*)boxK)[b * K_ + j];
  const float aj = __fmul_rn(__fsub_rn(v.z, v.x), __fsub_rn(v.w, v.y));
  float mx = 0.f;
  int lim = j - gi0;
  if (lim > 256) lim = 256;
  for (int ii = 0; ii < lim; ++ii) {
    float ltx = fmaxf(sx0[ii], v.x);
    float lty = fmaxf(sy0[ii], v.y);
    float rbx = fminf(sx1[ii], v.z);
    float rby = fminf(sy1[ii], v.w);
    float wx = fmaxf(__fsub_rn(rbx, ltx), 0.f);
    float wy = fmaxf(__fsub_rn(rby, lty), 0.f);
    float inter = __fmul_rn(wx, wy);
    if (inter > 0.f) {
      float uni = __fsub_rn(__fadd_rn(sa[ii], aj), inter);
      float iou = __fdiv_rn(inter, uni);
      mx = fmaxf(mx, iou);
    }
  }
  if (mx > 0.f) atomicMax(&maxiou[b * K_ + j], __float_as_uint(mx));
}

// ---------------------------------------------------------------------------
// Gather kept features into Xf32 [C][MP_] (pad columns m>=M_ set to 0).
__global__ __launch_bounds__(256) void k_gatherfeat(const int* __restrict__ keep_i,
                                                    const float* __restrict__ feat,
                                                    float* __restrict__ X) {
  const int t = blockIdx.x * 256 + threadIdx.x;  // t = c*MP_ + m
  const int m = t % MP_;
  const int c = t / MP_;
  float v = 0.f;
  if (m < M_) {
    const int b = m / K_;
    const int idx = keep_i[m];
    v = feat[((size_t)(b * C_ + c)) * N_ + idx];
  }
  X[t] = v;
}

// ---------------------------------------------------------------------------
// Split W (f32 [6][C][C]) into bf16 hi/lo (same layout).
__global__ __launch_bounds__(256) void k_prepW(const float* __restrict__ W,
                                               unsigned short* __restrict__ Whi,
                                               unsigned short* __restrict__ Wlo) {
  const int t = blockIdx.x * 256 + threadIdx.x;
  if (t >= 6 * C_ * C_) return;
  const float w = W[t];
  const unsigned short h = f2bf(w);
  Whi[t] = h;
  Wlo[t] = f2bf(__fsub_rn(w, bf2f(h)));
}

// ---------------------------------------------------------------------------
// Transpose Xf32 [C][MP_] -> Xt hi/lo [MP_][C] (bf16 split), 64x64 LDS tiles.
__global__ __launch_bounds__(256) void k_t2hilo(const float* __restrict__ X,
                                                unsigned short* __restrict__ Xhi,
                                                unsigned short* __restrict__ Xlo) {
  __shared__ float T[64][65];
  const int m0 = blockIdx.x * 64;
  const int c0 = blockIdx.y * 64;
  const int t = threadIdx.x;
  const int lm = t & 63;
  const int w4 = t >> 6;  // 0..3
#pragma unroll
  for (int r = 0; r < 16; ++r) {
    const int cl = r * 4 + w4;
    T[cl][lm] = X[(size_t)(c0 + cl) * MP_ + m0 + lm];
  }
  __syncthreads();
#pragma unroll
  for (int r = 0; r < 16; ++r) {
    const int ml = r * 4 + w4;
    const float v = T[lm][ml];
    const unsigned short h = f2bf(v);
    Xhi[(size_t)(m0 + ml) * C_ + c0 + lm] = h;
    Xlo[(size_t)(m0 + ml) * C_ + c0 + lm] = f2bf(__fsub_rn(v, bf2f(h)));
  }
}

// ---------------------------------------------------------------------------
// MLP layer: Y[m][o] = leaky_relu( sum_k Xt[m][k]*W[o][k] + bias[o] ), output
// written as bf16 hi/lo in Xt layout [MP_][C]. Split-bf16 3-term MFMA:
// hi*hi + hi*lo + lo*hi (lo*lo term ~2^-18 relative, dropped).
// Block tile 128m x 64o, 4 waves (2x2), per-wave 64m x 32o = 4x2 MFMA tiles.
#define LDSTRIDE 40  // shorts per 32-k row: 16B aligned, 2-way banks (free)
__global__ __launch_bounds__(256) void k_mlp(const unsigned short* __restrict__ Whi,
                                             const unsigned short* __restrict__ Wlo,
                                             const float* __restrict__ bias,
                                             const unsigned short* __restrict__ Xhi,
                                             const unsigned short* __restrict__ Xlo,
                                             unsigned short* __restrict__ Yhi,
                                             unsigned short* __restrict__ Ylo) {
  __shared__ char arena[128 * 68 * 4];  // 34816 B; staging needs 30720 B
  unsigned short* Xs_hi = (unsigned short*)arena;        // [128][40]
  unsigned short* Xs_lo = Xs_hi + 128 * LDSTRIDE;
  unsigned short* Ws_hi = Xs_lo + 128 * LDSTRIDE;        // [64][40]
  unsigned short* Ws_lo = Ws_hi + 64 * LDSTRIDE;
  float* Yt = (float*)arena;                             // [128][68] (reuse)

  const int m0 = blockIdx.x * 128;
  const int o0 = blockIdx.y * 64;
  const int t = threadIdx.x;
  const int lane = t & 63;
  const int wave = t >> 6;
  const int wm = wave & 1;      // m half (64)
  const int wo = wave >> 1;     // o half (32)
  const int quad = lane >> 4;
  const int l15 = lane & 15;

  // staging map: X segs 512/array -> rows t>>2 and 64+(t>>2), quad t&3
  const int xr = t >> 2, xq = (t & 3) * 8;

  f32x4 acc[4][2];
#pragma unroll
  for (int mi = 0; mi < 4; ++mi)
#pragma unroll
    for (int oi = 0; oi < 2; ++oi) acc[mi][oi] = (f32x4)0.f;

  uint4 sxh0, sxh1, sxl0, sxl1, swh, swl;
  // preload k-step 0
  {
    const int k0 = 0;
    sxh0 = *(const uint4*)&Xhi[(size_t)(m0 + xr) * C_ + k0 + xq];
    sxh1 = *(const uint4*)&Xhi[(size_t)(m0 + xr + 64) * C_ + k0 + xq];
    sxl0 = *(const uint4*)&Xlo[(size_t)(m0 + xr) * C_ + k0 + xq];
    sxl1 = *(const uint4*)&Xlo[(size_t)(m0 + xr + 64) * C_ + k0 + xq];
    swh  = *(const uint4*)&Whi[(size_t)(o0 + xr) * C_ + k0 + xq];
    swl  = *(const uint4*)&Wlo[(size_t)(o0 + xr) * C_ + k0 + xq];
  }
#pragma unroll
  for (int ks = 0; ks < 8; ++ks) {
    __syncthreads();  // previous iteration's frag reads complete
    *(uint4*)&Xs_hi[xr * LDSTRIDE + xq] = sxh0;
    *(uint4*)&Xs_hi[(xr + 64) * LDSTRIDE + xq] = sxh1;
    *(uint4*)&Xs_lo[xr * LDSTRIDE + xq] = sxl0;
    *(uint4*)&Xs_lo[(xr + 64) * LDSTRIDE + xq] = sxl1;
    *(uint4*)&Ws_hi[xr * LDSTRIDE + xq] = swh;
    *(uint4*)&Ws_lo[xr * LDSTRIDE + xq] = swl;
    __syncthreads();
    if (ks < 7) {  // prefetch next k-step while MFMA phase runs
      const int k1 = (ks + 1) * 32;
      sxh0 = *(const uint4*)&Xhi[(size_t)(m0 + xr) * C_ + k1 + xq];
      sxh1 = *(const uint4*)&Xhi[(size_t)(m0 + xr + 64) * C_ + k1 + xq];
      sxl0 = *(const uint4*)&Xlo[(size_t)(m0 + xr) * C_ + k1 + xq];
      sxl1 = *(const uint4*)&Xlo[(size_t)(m0 + xr + 64) * C_ + k1 + xq];
      swh  = *(const uint4*)&Whi[(size_t)(o0 + xr) * C_ + k1 + xq];
      swl  = *(const uint4*)&Wlo[(size_t)(o0 + xr) * C_ + k1 + xq];
    }
    bf16x8 Ah[4], Al[4], Bh[2], Bl[2];
#pragma unroll
    for (int mi = 0; mi < 4; ++mi) {
      const int row = (wm * 64 + mi * 16 + l15) * LDSTRIDE + quad * 8;
      Ah[mi] = *(const bf16x8*)&Xs_hi[row];
      Al[mi] = *(const bf16x8*)&Xs_lo[row];
    }
#pragma unroll
    for (int oi = 0; oi < 2; ++oi) {
      const int row = (wo * 32 + oi * 16 + l15) * LDSTRIDE + quad * 8;
      Bh[oi] = *(const bf16x8*)&Ws_hi[row];
      Bl[oi] = *(const bf16x8*)&Ws_lo[row];
    }
#pragma unroll
    for (int mi = 0; mi < 4; ++mi)
#pragma unroll
      for (int oi = 0; oi < 2; ++oi) {
        acc[mi][oi] = __builtin_amdgcn_mfma_f32_16x16x32_bf16(Ah[mi], Bh[oi], acc[mi][oi], 0, 0, 0);
        acc[mi][oi] = __builtin_amdgcn_mfma_f32_16x16x32_bf16(Ah[mi], Bl[oi], acc[mi][oi], 0, 0, 0);
        acc[mi][oi] = __builtin_amdgcn_mfma_f32_16x16x32_bf16(Al[mi], Bh[oi], acc[mi][oi], 0, 0, 0);
      }
  }
  // epilogue: bias + leaky, stash f32 tile in LDS, then coalesced hi/lo store
  const float b0 = bias[o0 + wo * 32 + l15];
  const float b1 = bias[o0 + wo * 32 + 16 + l15];
  __syncthreads();  // done with staging LDS; reuse as Yt
#pragma unroll
  for (int mi = 0; mi < 4; ++mi)
#pragma unroll
    for (int oi = 0; oi < 2; ++oi) {
      const float bb = oi ? b1 : b0;
#pragma unroll
      for (int r = 0; r < 4; ++r) {
        float y = acc[mi][oi][r] + bb;
        y = fmaxf(y, 0.2f * y);
        Yt[(wm * 64 + mi * 16 + quad * 4 + r) * 68 + wo * 32 + oi * 16 + l15] = y;
      }
    }
  __syncthreads();
  const int ml = t & 127, oh = t >> 7;  // thread: row ml, o-half oh (32 wide)
  unsigned short hbuf[32], lbuf[32];
#pragma unroll
  for (int i = 0; i < 32; i += 4) {
    f32x4 v = *(const f32x4*)&Yt[ml * 68 + oh * 32 + i];
#pragma unroll
    for (int jj = 0; jj < 4; ++jj) {
      const unsigned short h = f2bf(v[jj]);
      hbuf[i + jj] = h;
      lbuf[i + jj] = f2bf(__fsub_rn(v[jj], bf2f(h)));
    }
  }
  const size_t obase = (size_t)(m0 + ml) * C_ + o0 + oh * 32;
#pragma unroll
  for (int i = 0; i < 32; i += 8) {
    *(uint4*)&Yhi[obase + i] = *(const uint4*)&hbuf[i];
    *(uint4*)&Ylo[obase + i] = *(const uint4*)&lbuf[i];
  }
}

// ---------------------------------------------------------------------------
// Final: logits = Wf @ x + bf (3 rows), softmax over 3, masked sum by max-iou.
__global__ __launch_bounds__(256) void k_final(const unsigned short* __restrict__ Xhi,
                                               const unsigned short* __restrict__ Xlo,
                                               const float* __restrict__ Wf,
                                               const float* __restrict__ bf,
                                               const unsigned* __restrict__ maxiou,
                                               float* __restrict__ out_loc) {
  __shared__ float sw[3 * 256];
  const int tid = threadIdx.x;
  sw[tid] = Wf[tid];
  sw[256 + tid] = Wf[256 + tid];
  sw[512 + tid] = Wf[512 + tid];
  __syncthreads();
  const int m = blockIdx.x * 256 + tid;
  if (m >= M_) return;
  float a0 = 0.f, a1 = 0.f, a2 = 0.f;
  const unsigned short* xh = Xhi + (size_t)m * C_;
  const unsigned short* xl = Xlo + (size_t)m * C_;
#pragma unroll 4
  for (int c = 0; c < C_; c += 8) {
    uint4 hv = *(const uint4*)&xh[c];
    uint4 lv = *(const uint4*)&xl[c];
    const unsigned hw[4] = {hv.x, hv.y, hv.z, hv.w};
    const unsigned lw[4] = {lv.x, lv.y, lv.z, lv.w};
#pragma unroll
    for (int q = 0; q < 4; ++q) {
      const float x0 = __uint_as_float((hw[q] & 0xffffu) << 16) +
                       __uint_as_float((lw[q] & 0xffffu) << 16);
      const float x1 = __uint_as_float(hw[q] & 0xffff0000u) +
                       __uint_as_float(lw[q] & 0xffff0000u);
      const int cc = c + q * 2;
      a0 += sw[cc] * x0 + sw[cc + 1] * x1;
      a1 += sw[256 + cc] * x0 + sw[256 + cc + 1] * x1;
      a2 += sw[512 + cc] * x0 + sw[512 + cc + 1] * x1;
    }
  }
  a0 += bf[0]; a1 += bf[1]; a2 += bf[2];
  const float mxv = fmaxf(a0, fmaxf(a1, a2));
  const float e0 = expf(a0 - mxv);
  const float e1 = expf(a1 - mxv);
  const float e2 = expf(a2 - mxv);
  const float inv = 1.f / (e0 + e1 + e2);
  const float miou = __uint_as_float(maxiou[m]);
  float loc = 0.f;
  if (miou < 0.4f) loc += e0;
  if (miou < 0.6f) loc += e1;
  if (miou < 0.8f) loc += e2;
  out_loc[m] = loc * inv;
}

// ---------------------------------------------------------------------------
extern "C" void kernel_launch(void* const* d_in, const int* in_sizes, int n_in,
                              void* d_out, int out_size, void* d_ws, size_t ws_size,
                              hipStream_t stream) {
  const float* box   = (const float*)d_in[0];
  const float* score = (const float*)d_in[1];
  const float* feat  = (const float*)d_in[2];
  const float* W     = (const float*)d_in[3];
  const float* bias  = (const float*)d_in[4];
  const float* Wf    = (const float*)d_in[5];
  const float* bf    = (const float*)d_in[6];

  float* out = (float*)d_out;
  float* out_loc  = out;        // [B*K]
  float* out_keep = out + M_;   // [B*K] keep as float

  // Workspace layout (~21.75 MB total)
  char* ws = (char*)d_ws;
  int*            keep_i = (int*)(ws + 0);                    // 40000
  float*          boxK   = (float*)(ws + 40960);              // 160000
  unsigned*       maxiou = (unsigned*)(ws + 204800);          // 40000
  unsigned short* Whi    = (unsigned short*)(ws + 245760);    // 786432
  unsigned short* Wlo    = (unsigned short*)(ws + 1032192);   // 786432
  unsigned short* XtA_hi = (unsigned short*)(ws + 1835008);   // 5242880
  unsigned short* XtA_lo = (unsigned short*)(ws + 7077888);   // 5242880
  unsigned short* XtB_hi = (unsigned short*)(ws + 12320768);  // 5242880
  unsigned short* XtB_lo = (unsigned short*)(ws + 17563648);  // 5242880 -> 22806528
  // Aliases (dead before first GEMM writes XtB):
  float* Xf32 = (float*)(ws + 12320768);  // [C][MP_] f32, 10485760 B
  int*   cnt  = (int*)(ws + 12320768);    // [B][N] ranks (dead before gatherfeat)

  k_prepW<<<(6 * C_ * C_ + 255) / 256, 256, 0, stream>>>(W, Whi, Wlo);
  k_zero<<<(B_ * N_ + 255) / 256, 256, 0, stream>>>(cnt);
  k_count<<<dim3(NT_, NCH_, B_), 256, 0, stream>>>(score, cnt);
  k_scatter<<<dim3(NT_, B_), 256, 0, stream>>>(cnt, keep_i, out_keep);
  k_gatherbox<<<(B_ * K_ + 255) / 256, 256, 0, stream>>>(keep_i, box, boxK, maxiou);
  k_iou<<<dim3((K_ + 255) / 256, (K_ + 255) / 256, B_), 256, 0, stream>>>(boxK, maxiou);
  k_gatherfeat<<<(C_ * MP_) / 256, 256, 0, stream>>>(keep_i, feat, Xf32);
  k_t2hilo<<<dim3(MP_ / 64, C_ / 64), 256, 0, stream>>>(Xf32, XtA_hi, XtA_lo);

  const unsigned short* xih = XtA_hi; const unsigned short* xil = XtA_lo;
  unsigned short* xoh = XtB_hi;       unsigned short* xol = XtB_lo;
  for (int l = 0; l < 6; ++l) {
    k_mlp<<<dim3(MP_ / 128, C_ / 64), 256, 0, stream>>>(
        Whi + (size_t)l * C_ * C_, Wlo + (size_t)l * C_ * C_,
        bias + (size_t)l * C_, xih, xil, xoh, xol);
    const unsigned short* th = xoh; const unsigned short* tl = xol;
    xoh = (unsigned short*)xih; xol = (unsigned short*)xil;
    xih = th; xil = tl;
  }
  // after 6 layers activations are in XtA (xih/xil point at it)

  k_final<<<(M_ + 255) / 256, 256, 0, stream>>>(xih, xil, Wf, bf, maxiou, out_loc);
}